// Round 5
// baseline (326.763 us; speedup 1.0000x reference)
//
#include <hip/hip_runtime.h>
#include <hip/hip_bf16.h>

#define BB 16
#define NN 10
#define CC 128
#define HWD 2304            // 48*48
#define DD (CC*HWD)         // 294912
#define NC (NN*CC)          // 1280
#define CHK 36              // chunks per (b,n) for dot kernel
#define CHUNK (DD/CHK)      // 8192

#define BM 256
#define BN 256
#define BK 64
#define TK (NC/BK)          // 20 K-tiles

typedef __bf16 bf16x8 __attribute__((ext_vector_type(8)));
typedef float  f32x4  __attribute__((ext_vector_type(4)));

#define FEAT_BYTES ((size_t)BB*HWD*NC*2)     // 94,371,840
#define WB_BYTES   ((size_t)NC*NC*2)         // 3,276,800
#define PART_FLOATS (BB*NN*CHK*3)            // 17,280

__device__ __forceinline__ ushort f2bf(float f) {
    __hip_bfloat16 h = __float2bfloat16(f);
    return *reinterpret_cast<ushort*>(&h);
}

__device__ __forceinline__ void gload_lds16(const ushort* g, ushort* l) {
    __builtin_amdgcn_global_load_lds(
        (const __attribute__((address_space(1))) void*)(const void*)g,
        (__attribute__((address_space(3))) void*)(void*)l,
        16, 0, 0);
}

// ---------------- Kernel 1: partial dots d0,d1,d2 ----------------
// grid ordered n-fastest: blocks sharing (b,ch) across n are adjacent -> the
// 3 shifted streams hit the same XCD's L2.
__global__ __launch_bounds__(256) void k_dots(const float* __restrict__ x,
                                              float* __restrict__ part) {
    int blk = blockIdx.x;
    int n  = blk % NN;
    int rest = blk / NN;
    int ch = rest % CHK;
    int b  = rest / CHK;
    int bn = b*NN + n;
    int n1 = (n + 1) % NN, n2 = (n + 2) % NN;
    const float* p0 = x + ((size_t)b*NN + n )*DD + (size_t)ch*CHUNK;
    const float* p1 = x + ((size_t)b*NN + n1)*DD + (size_t)ch*CHUNK;
    const float* p2 = x + ((size_t)b*NN + n2)*DD + (size_t)ch*CHUNK;
    int t = threadIdx.x;
    float s0 = 0.f, s1 = 0.f, s2 = 0.f;
    #pragma unroll
    for (int i = 0; i < CHUNK/1024; ++i) {
        int off = i*1024 + t*4;
        float4 a = *(const float4*)(p0 + off);
        float4 u = *(const float4*)(p1 + off);
        float4 v = *(const float4*)(p2 + off);
        s0 += a.x*a.x + a.y*a.y + a.z*a.z + a.w*a.w;
        s1 += a.x*u.x + a.y*u.y + a.z*u.z + a.w*u.w;
        s2 += a.x*v.x + a.y*v.y + a.z*v.z + a.w*v.w;
    }
    for (int o = 32; o > 0; o >>= 1) {
        s0 += __shfl_down(s0, o);
        s1 += __shfl_down(s1, o);
        s2 += __shfl_down(s2, o);
    }
    __shared__ float red[4][3];
    int w = t >> 6, l = t & 63;
    if (l == 0) { red[w][0] = s0; red[w][1] = s1; red[w][2] = s2; }
    __syncthreads();
    if (t == 0) {
        float r0 = 0.f, r1 = 0.f, r2 = 0.f;
        for (int i = 0; i < 4; ++i) { r0 += red[i][0]; r1 += red[i][1]; r2 += red[i][2]; }
        float* o = part + ((size_t)bn*CHK + ch)*3;
        o[0] = r0; o[1] = r1; o[2] = r2;
    }
}

// ---------------- Kernel 2: softmax -> combination coefficients ----------------
__global__ void k_coef(const float* __restrict__ part,
                       const float* __restrict__ pos_dec,
                       const float* __restrict__ len_dec,
                       float* __restrict__ coef) {
    int bn = threadIdx.x;
    if (bn >= BB*NN) return;
    int n = bn % NN;
    float d0 = 0.f, d1 = 0.f, d2 = 0.f;
    const float* p = part + (size_t)bn*CHK*3;
    for (int i = 0; i < CHK; ++i) { d0 += p[i*3]; d1 += p[i*3+1]; d2 += p[i*3+2]; }
    float pd = pos_dec[n], ld = len_dec[n];
    float l0 = (1.f - pd)*d0 + pd*d1;
    float l1 = ld*((1.f - pd)*d1 + pd*d2);
    float m  = fmaxf(l0, l1);
    float e0 = expf(l0 - m), e1 = expf(l1 - m);
    float inv = 1.f/(e0 + e1);
    float a0 = e0*inv, a1 = e1*inv;
    coef[bn*3+0] = a0*(1.f - pd);
    coef[bn*3+1] = a0*pd + a1*ld*(1.f - pd);
    coef[bn*3+2] = a1*ld*pd;
}

// ---------------- Kernel 3: conv_w fp32 -> bf16 ----------------
__global__ __launch_bounds__(256) void k_wconv(const float* __restrict__ w,
                                               ushort* __restrict__ wb) {
    int i = blockIdx.x*blockDim.x + threadIdx.x;
    size_t idx = (size_t)i*4;
    if (idx >= (size_t)NC*NC) return;
    float4 a = *(const float4*)(w + idx);
    ushort4 o;
    o.x = f2bf(a.x); o.y = f2bf(a.y); o.z = f2bf(a.z); o.w = f2bf(a.w);
    *(ushort4*)(wb + idx) = o;
}

// ---------------- Kernel 4: featT[b][hw][c] bf16 (transposed combo) ----------------
__global__ __launch_bounds__(256) void k_feat(const float* __restrict__ x,
                                              const float* __restrict__ coef,
                                              ushort* __restrict__ featT) {
    __shared__ float tile[32*129];
    int hwt = blockIdx.x;         // 0..71
    int n   = blockIdx.y;         // 0..9
    int b   = blockIdx.z;         // 0..15
    int bn  = b*NN + n;
    float c0 = coef[bn*3+0], c1 = coef[bn*3+1], c2 = coef[bn*3+2];
    int n1 = (n + 1) % NN, n2 = (n + 2) % NN;
    const float* p0 = x + ((size_t)b*NN + n )*DD;
    const float* p1 = x + ((size_t)b*NN + n1)*DD;
    const float* p2 = x + ((size_t)b*NN + n2)*DD;
    int t = threadIdx.x;
    int hw0 = hwt*32;

    int ccl = t >> 3;             // 0..31
    int hwi = (t & 7) * 4;        // 0..28
    #pragma unroll
    for (int p = 0; p < 4; ++p) {
        int cc = p*32 + ccl;
        size_t off = (size_t)cc*HWD + hw0 + hwi;
        float4 a = *(const float4*)(p0 + off);
        float4 u = *(const float4*)(p1 + off);
        float4 v = *(const float4*)(p2 + off);
        tile[(hwi+0)*129 + cc] = c0*a.x + c1*u.x + c2*v.x;
        tile[(hwi+1)*129 + cc] = c0*a.y + c1*u.y + c2*v.y;
        tile[(hwi+2)*129 + cc] = c0*a.z + c1*u.z + c2*v.z;
        tile[(hwi+3)*129 + cc] = c0*a.w + c1*u.w + c2*v.w;
    }
    __syncthreads();

    int hwl = t >> 4;             // 0..15
    int cc0 = (t & 15) * 8;       // 0..120
    #pragma unroll
    for (int p = 0; p < 2; ++p) {
        int hw = p*16 + hwl;
        const float* src = &tile[hw*129 + cc0];
        union { ushort us[8]; uint4 v; } pk;
        #pragma unroll
        for (int j = 0; j < 8; ++j) pk.us[j] = f2bf(src[j]);
        ushort* dst = featT + (size_t)b*HWD*NC + (size_t)(hw0 + hw)*NC + n*CC + cc0;
        *(uint4*)dst = pk.v;
    }
}

// ---------------- Kernel 5: 256x256x64 GEMM, 4-phase/K-tile, k-half regions ----------------
// LDS: L[buf][region][256 rows * 32 k], region 0=Ak0 1=Bk0 2=Ak1 3=Bk1.
// Within a region: ushort idx = row*32 + phys_chunk*8, phys_chunk = c ^ ((row>>1)&3).
// Stage order per tile t (for t+1): ph1 Ak0, ph2 Bk0, ph3 Ak1, ph4 Bk1.
// Waits: vmcnt(4) at end of ph2 (protects ph3's Ak1/Bk1 reads) and end of ph4
// (protects next tile's Ak0/Bk0 reads). Leads >= 2 phases; never drained to 0
// in steady state.
__global__ __launch_bounds__(512, 2) void k_gemm(const ushort* __restrict__ Wb,
                                                 const ushort* __restrict__ featT,
                                                 const float* __restrict__ bias,
                                                 const float* __restrict__ x,
                                                 float* __restrict__ out) {
    __shared__ ushort L[2][4][BM*32];   // 2 bufs x 4 regions x 16 KiB = 128 KiB

    int bid = blockIdx.x;
    int wkid = (bid & 7) * 90 + (bid >> 3);   // bijective XCD swizzle (720 = 8*90)
    int b   = wkid / 45;
    int r45 = wkid % 45;
    int hwt = r45 / 5;
    int ot  = r45 % 5;
    int o0 = ot*BM, hw0 = hwt*BN;

    int t = threadIdx.x;
    int l = t & 63;
    int w = t >> 6;
    int wr = w >> 2, wc = w & 3;      // 2 x 4 wave grid

    const ushort* Ag = Wb + (size_t)o0*NC;
    const ushort* Bg = featT + (size_t)b*HWD*NC + (size_t)hw0*NC;

    // staging constants: slots s0=t, s1=t+512 in a 1024-slot region
    int r0 = t >> 2, c0 = t & 3;
    int r1 = r0 + 128, c1 = c0;
    int sw = (t >> 3) & 3;                       // ((r>>1)&3), same for r0 and r1
    size_t g0 = (size_t)r0*NC + (size_t)((c0 ^ sw) * 8);
    size_t g1 = (size_t)r1*NC + (size_t)((c1 ^ sw) * 8);

#define STAGE(gbase_, nb_, reg_, tile_, q_) do { \
    ushort* d_ = &L[nb_][reg_][0]; \
    size_t ko_ = (size_t)(tile_)*BK + (q_)*32; \
    gload_lds16((gbase_) + g0 + ko_, d_ + t*8); \
    gload_lds16((gbase_) + g1 + ko_, d_ + (512 + t)*8); } while (0)

    // fragment read constants
    int fr = l & 15;                  // row low bits
    int fsw = (l >> 1) & 3;           // ((row>>1)&3)
    int kc = ((l >> 4) ^ fsw) * 8;    // swizzled chunk offset (ushorts)
    int rowA0 = wr*128 + fr;
    int rowB0 = wc*64 + fr;

    f32x4 acc[8][4] = {};

    // prologue: stage tile 0 (8 loads), wait Ak0,Bk0 done
    STAGE(Ag, 0, 0, 0, 0); STAGE(Bg, 0, 1, 0, 0);
    STAGE(Ag, 0, 2, 0, 1); STAGE(Bg, 0, 3, 0, 1);
    asm volatile("s_waitcnt vmcnt(4)" ::: "memory");
    __builtin_amdgcn_s_barrier();
    __builtin_amdgcn_sched_barrier(0);

    bf16x8 b0f[4], b1f[4], af[4];

    for (int kt = 0; kt < TK; ++kt) {
        int buf = kt & 1, nbuf = buf ^ 1;
        const ushort* A0r = &L[buf][0][0];
        const ushort* B0r = &L[buf][1][0];
        const ushort* A1r = &L[buf][2][0];
        const ushort* B1r = &L[buf][3][0];
        bool more = (kt + 1 < TK);

        // ---- phase 1: (mq0, k0) ----
        #pragma unroll
        for (int n = 0; n < 4; ++n)
            b0f[n] = *(const bf16x8*)&B0r[(rowB0 + n*16)*32 + kc];
        #pragma unroll
        for (int i = 0; i < 4; ++i)
            af[i] = *(const bf16x8*)&A0r[(rowA0 + i*16)*32 + kc];
        if (more) STAGE(Ag, nbuf, 0, kt+1, 0);
        __builtin_amdgcn_sched_barrier(0);
        __builtin_amdgcn_s_barrier();
        __builtin_amdgcn_sched_barrier(0);
        __builtin_amdgcn_s_setprio(1);
        #pragma unroll
        for (int i = 0; i < 4; ++i)
            #pragma unroll
            for (int n = 0; n < 4; ++n)
                acc[i][n] = __builtin_amdgcn_mfma_f32_16x16x32_bf16(af[i], b0f[n], acc[i][n], 0, 0, 0);
        __builtin_amdgcn_s_setprio(0);
        __builtin_amdgcn_sched_barrier(0);
        __builtin_amdgcn_s_barrier();
        __builtin_amdgcn_sched_barrier(0);

        // ---- phase 2: (mq1, k0) ----
        #pragma unroll
        for (int i = 0; i < 4; ++i)
            af[i] = *(const bf16x8*)&A0r[(rowA0 + 64 + i*16)*32 + kc];
        if (more) STAGE(Bg, nbuf, 1, kt+1, 0);
        __builtin_amdgcn_sched_barrier(0);
        __builtin_amdgcn_s_barrier();
        __builtin_amdgcn_sched_barrier(0);
        __builtin_amdgcn_s_setprio(1);
        #pragma unroll
        for (int i = 0; i < 4; ++i)
            #pragma unroll
            for (int n = 0; n < 4; ++n)
                acc[4+i][n] = __builtin_amdgcn_mfma_f32_16x16x32_bf16(af[i], b0f[n], acc[4+i][n], 0, 0, 0);
        __builtin_amdgcn_s_setprio(0);
        __builtin_amdgcn_sched_barrier(0);
        if (more) asm volatile("s_waitcnt vmcnt(4)" ::: "memory");  // Ak1,Bk1 of kt ready
        else      asm volatile("s_waitcnt vmcnt(0)" ::: "memory");
        __builtin_amdgcn_s_barrier();
        __builtin_amdgcn_sched_barrier(0);

        // ---- phase 3: (mq0, k1) ----
        #pragma unroll
        for (int n = 0; n < 4; ++n)
            b1f[n] = *(const bf16x8*)&B1r[(rowB0 + n*16)*32 + kc];
        #pragma unroll
        for (int i = 0; i < 4; ++i)
            af[i] = *(const bf16x8*)&A1r[(rowA0 + i*16)*32 + kc];
        if (more) STAGE(Ag, nbuf, 2, kt+1, 1);
        __builtin_amdgcn_sched_barrier(0);
        __builtin_amdgcn_s_barrier();
        __builtin_amdgcn_sched_barrier(0);
        __builtin_amdgcn_s_setprio(1);
        #pragma unroll
        for (int i = 0; i < 4; ++i)
            #pragma unroll
            for (int n = 0; n < 4; ++n)
                acc[i][n] = __builtin_amdgcn_mfma_f32_16x16x32_bf16(af[i], b1f[n], acc[i][n], 0, 0, 0);
        __builtin_amdgcn_s_setprio(0);
        __builtin_amdgcn_sched_barrier(0);
        __builtin_amdgcn_s_barrier();
        __builtin_amdgcn_sched_barrier(0);

        // ---- phase 4: (mq1, k1) ----
        #pragma unroll
        for (int i = 0; i < 4; ++i)
            af[i] = *(const bf16x8*)&A1r[(rowA0 + 64 + i*16)*32 + kc];
        if (more) STAGE(Bg, nbuf, 3, kt+1, 1);
        __builtin_amdgcn_sched_barrier(0);
        __builtin_amdgcn_s_barrier();
        __builtin_amdgcn_sched_barrier(0);
        __builtin_amdgcn_s_setprio(1);
        #pragma unroll
        for (int i = 0; i < 4; ++i)
            #pragma unroll
            for (int n = 0; n < 4; ++n)
                acc[4+i][n] = __builtin_amdgcn_mfma_f32_16x16x32_bf16(af[i], b1f[n], acc[4+i][n], 0, 0, 0);
        __builtin_amdgcn_s_setprio(0);
        __builtin_amdgcn_sched_barrier(0);
        if (more) asm volatile("s_waitcnt vmcnt(4)" ::: "memory");  // Ak0,Bk0 of kt+1 ready
        __builtin_amdgcn_s_barrier();
        __builtin_amdgcn_sched_barrier(0);
    }
#undef STAGE

    // epilogue: + bias + residual x
    #pragma unroll
    for (int m = 0; m < 8; ++m) {
        int ro_base = o0 + wr*128 + m*16 + ((l >> 4) << 2);
        #pragma unroll
        for (int n = 0; n < 4; ++n) {
            int col = hw0 + wc*64 + n*16 + (l & 15);
            #pragma unroll
            for (int r = 0; r < 4; ++r) {
                int ro = ro_base + r;
                size_t idx = (size_t)b*NC*HWD + (size_t)ro*HWD + col;
                out[idx] = acc[m][n][r] + bias[ro] + x[idx];
            }
        }
    }
}

extern "C" void kernel_launch(void* const* d_in, const int* in_sizes, int n_in,
                              void* d_out, int out_size, void* d_ws, size_t ws_size,
                              hipStream_t stream) {
    const float* x       = (const float*)d_in[0];
    const float* pos_dec = (const float*)d_in[1];
    const float* len_dec = (const float*)d_in[2];
    const float* conv_w  = (const float*)d_in[3];
    const float* conv_b  = (const float*)d_in[4];
    float* out = (float*)d_out;

    char* ws = (char*)d_ws;
    ushort* featT = (ushort*)ws;                                   // 94,371,840 B
    ushort* wb    = (ushort*)(ws + FEAT_BYTES);                    // 3,276,800 B
    float*  part  = (float*)(ws + FEAT_BYTES + WB_BYTES);          // 69,120 B
    float*  coef  = part + PART_FLOATS;                            // 1,920 B

    k_dots <<<dim3(BB*NN*CHK), 256, 0, stream>>>(x, part);
    k_coef <<<dim3(1), 256, 0, stream>>>(part, pos_dec, len_dec, coef);
    k_wconv<<<dim3(1600), 256, 0, stream>>>(conv_w, wb);
    k_feat <<<dim3(72, NN, BB), 256, 0, stream>>>(x, coef, featT);
    k_gemm <<<dim3(720), 512, 0, stream>>>(wb, featT, conv_b, x, out);
}